// Round 5
// baseline (427.035 us; speedup 1.0000x reference)
//
#include <hip/hip_runtime.h>

// VQ codebook: z_e (262144, 64) f32, embeddings (512, 64) f32.
// Outputs (flat f32 in d_out): z_q_st [N*D], indices-as-float [N], loss [1].
//
// R5: registers hold acc[32] (one 32-code panel), NOT the token row.
// R1-R4 lesson: allocator pins 64 VGPR/thread (8 waves/EU) and spills any
// 64-float z row (WRITE_SIZE +90MB canary, 68% stall). Here:
//   - z streams from a padded LDS tile (stride 65 -> 2-way bank = free),
//     1 ds_read_b32 per d, reused by 32 FMAs.
//   - e streams from a TRANSPOSED codebook embT[d][c] via wave-uniform
//     s_load (32 consecutive floats/d) -> SGPR operand in v_fmac. SGPR
//     broadcast is the only operand path that doesn't burn LDS/VMEM pipes.
//   - per-thread need ~45 VGPR < 64 -> no spill by construction.

static constexpr int N_TOK   = 262144;
static constexpr int K       = 512;
static constexpr int D       = 64;
static constexpr int BLK     = 256;          // threads = tokens per block
static constexpr int NBLK    = N_TOK / BLK;  // 1024
static constexpr int PANEL   = 32;           // codes per register panel
static constexpr int NPANEL  = K / PANEL;    // 16
static constexpr int ZSTRIDE = D + 1;        // 65 (odd) -> conflict-free b32

// ---- prep 0: esq[k] = ||e_k||^2 --------------------------------------------
__global__ void esq_kernel(const float* __restrict__ emb, float* __restrict__ esq) {
  int k = threadIdx.x;
  if (k < K) {
    const float4* row = reinterpret_cast<const float4*>(emb + (size_t)k * D);
    float s = 0.f;
#pragma unroll
    for (int i = 0; i < D / 4; ++i) {
      float4 v = row[i];
      s = fmaf(v.x, v.x, s);
      s = fmaf(v.y, v.y, s);
      s = fmaf(v.z, v.z, s);
      s = fmaf(v.w, v.w, s);
    }
    esq[k] = s;
  }
}

// ---- prep 1: embT[d][c] = emb[c][d] ----------------------------------------
__global__ __launch_bounds__(512) void embT_kernel(
    const float* __restrict__ emb, float* __restrict__ embT) {
  int idx = blockIdx.x * 512 + threadIdx.x;  // 64 blocks x 512 = 32768
  int d = idx >> 9;        // / 512
  int c = idx & 511;       // % 512
  embT[idx] = emb[c * D + d];  // write coalesced; read L2-hot (128 KiB)
}

// ---- main: per-token argmin + gather + partial loss ------------------------
__global__ __launch_bounds__(BLK) void vq_main(
    const float* __restrict__ z_e, const float* __restrict__ emb,
    const float* __restrict__ embT, const float* __restrict__ esq,
    float* __restrict__ out_zq, float* __restrict__ out_idx,
    float* __restrict__ block_loss) {
  __shared__ float zs[BLK * ZSTRIDE];  // 256*65*4 = 66.6 KiB
  __shared__ float red[BLK];

  const int t  = threadIdx.x;
  const int n0 = blockIdx.x * BLK;

  // Coalesced staging: linear float4 reads, scalar scatter into padded LDS.
  {
    const float4* Z4 = reinterpret_cast<const float4*>(z_e + (size_t)n0 * D);
#pragma unroll
    for (int i = 0; i < (BLK * D / 4) / BLK; ++i) {  // 16 iters
      int off = i * BLK + t;        // float4 index within block tile
      float4 v = Z4[off];
      int tok = off >> 4;           // 16 float4 per token
      int d4  = (off & 15) << 2;
      float* p = &zs[tok * ZSTRIDE + d4];
      p[0] = v.x; p[1] = v.y; p[2] = v.z; p[3] = v.w;
    }
  }
  __syncthreads();

  const float* zrow = &zs[t * ZSTRIDE];

  float best = 3.402823466e38f;
  int   bidx = 0;

  for (int p = 0; p < NPANEL; ++p) {
    const float* ET = embT + p * PANEL;  // column block; row stride K
    float acc[PANEL];
#pragma unroll
    for (int c = 0; c < PANEL; ++c) acc[c] = 0.f;

#pragma unroll 2
    for (int d = 0; d < D; ++d) {
      float zd = zrow[d];                    // ds_read_b32, 2-way bank = free
      const float* e = ET + (size_t)d * K;   // wave-uniform -> s_load x2
#pragma unroll
      for (int c = 0; c < PANEL; ++c)
        acc[c] = fmaf(zd, e[c], acc[c]);     // SGPR operand broadcast
    }

    const float* es = esq + p * PANEL;       // wave-uniform
#pragma unroll
    for (int c = 0; c < PANEL; ++c) {
      float s = fmaf(-2.f, acc[c], es[c]);
      // Ascending panel/c order + strict < == jnp.argmin first-min ties.
      if (s < best) { best = s; bidx = p * PANEL + c; }
    }
  }

  // Gather chosen code (divergent, codebook is L2-hot).
  // st = z + (q - z) computed literally (matches reference expression).
  float lsum = 0.f;
  {
    const float4* er = reinterpret_cast<const float4*>(emb + (size_t)bidx * D);
    float4* orow = reinterpret_cast<float4*>(out_zq + (size_t)(n0 + t) * D);
#pragma unroll
    for (int i = 0; i < D / 4; ++i) {
      float4 q = er[i];
      float z0 = zrow[4 * i + 0], z1 = zrow[4 * i + 1];
      float z2 = zrow[4 * i + 2], z3 = zrow[4 * i + 3];
      float dx = q.x - z0, dy = q.y - z1, dz = q.z - z2, dw = q.w - z3;
      float4 st;
      st.x = z0 + dx; st.y = z1 + dy; st.z = z2 + dz; st.w = z3 + dw;
      orow[i] = st;
      lsum = fmaf(dx, dx, lsum);
      lsum = fmaf(dy, dy, lsum);
      lsum = fmaf(dz, dz, lsum);
      lsum = fmaf(dw, dw, lsum);
    }
  }

  out_idx[n0 + t] = (float)bidx;

  // Deterministic per-block loss reduction.
  red[t] = lsum;
  __syncthreads();
#pragma unroll
  for (int off = BLK / 2; off > 0; off >>= 1) {
    if (t < off) red[t] += red[t + off];
    __syncthreads();
  }
  if (t == 0) block_loss[blockIdx.x] = red[0];
}

// ---- finalize loss (deterministic tree) ------------------------------------
__global__ __launch_bounds__(256) void loss_finalize(
    const float* __restrict__ bl, float* __restrict__ out_loss) {
  __shared__ float sm[256];
  float s = 0.f;
  for (int i = threadIdx.x; i < NBLK; i += 256) s += bl[i];
  sm[threadIdx.x] = s;
  __syncthreads();
#pragma unroll
  for (int off = 128; off > 0; off >>= 1) {
    if (threadIdx.x < off) sm[threadIdx.x] += sm[threadIdx.x + off];
    __syncthreads();
  }
  if (threadIdx.x == 0) out_loss[0] = sm[0] * (1.0f / 16777216.0f);  // /(N*D)
}

extern "C" void kernel_launch(void* const* d_in, const int* in_sizes, int n_in,
                              void* d_out, int out_size, void* d_ws, size_t ws_size,
                              hipStream_t stream) {
  const float* z_e = (const float*)d_in[0];
  const float* emb = (const float*)d_in[1];

  float* out      = (float*)d_out;
  float* out_zq   = out;                          // N*D
  float* out_idx  = out + (size_t)N_TOK * D;      // N
  float* out_loss = out_idx + N_TOK;              // 1

  float* esq  = (float*)d_ws;            // K floats
  float* bl   = esq + K;                 // NBLK floats
  float* embT = bl + NBLK;               // K*D floats (128 KiB)

  esq_kernel<<<1, K, 0, stream>>>(emb, esq);
  embT_kernel<<<(K * D) / 512, 512, 0, stream>>>(emb, embT);
  vq_main<<<NBLK, BLK, 0, stream>>>(z_e, emb, embT, esq, out_zq, out_idx, bl);
  loss_finalize<<<1, 256, 0, stream>>>(bl, out_loss);
}

// Round 6
// 328.727 us; speedup vs baseline: 1.2991x; 1.2991x over previous
//
#include <hip/hip_runtime.h>

// VQ codebook: z_e (262144, 64) f32, embeddings (512, 64) f32.
// Outputs (flat f32 in d_out): z_q_st [N*D], indices-as-float [N], loss [1].
//
// R6: acc[32]-panel in VGPRs + SGPR-broadcast embT (as R5), but NO LDS z-tile:
// z streams from GLOBAL per panel (16 re-reads, L2/L3-hot; ~30us aggregate).
// R5 lesson: 67.6KB LDS tile -> 2 waves/SIMD -> latency-bound at 32% VALUBusy.
// Here LDS ~= 1KB -> occupancy bounded only by VGPRs (~55/thread); the
// per-panel load:FMA issue ratio is 1:64 so VMEM latency hides under FMAs
// with >=4 waves/SIMD. Arithmetic order per code identical to R5 (absmax 0).

static constexpr int N_TOK   = 262144;
static constexpr int K       = 512;
static constexpr int D       = 64;
static constexpr int BLK     = 256;
static constexpr int NBLK    = N_TOK / BLK;  // 1024
static constexpr int PANEL   = 32;
static constexpr int NPANEL  = K / PANEL;    // 16

// ---- prep 0: esq[k] = ||e_k||^2 --------------------------------------------
__global__ void esq_kernel(const float* __restrict__ emb, float* __restrict__ esq) {
  int k = threadIdx.x;
  if (k < K) {
    const float4* row = reinterpret_cast<const float4*>(emb + (size_t)k * D);
    float s = 0.f;
#pragma unroll
    for (int i = 0; i < D / 4; ++i) {
      float4 v = row[i];
      s = fmaf(v.x, v.x, s);
      s = fmaf(v.y, v.y, s);
      s = fmaf(v.z, v.z, s);
      s = fmaf(v.w, v.w, s);
    }
    esq[k] = s;
  }
}

// ---- prep 1: embT[d][c] = emb[c][d] ----------------------------------------
__global__ __launch_bounds__(512) void embT_kernel(
    const float* __restrict__ emb, float* __restrict__ embT) {
  int idx = blockIdx.x * 512 + threadIdx.x;  // 64 blocks x 512
  int d = idx >> 9;
  int c = idx & 511;
  embT[idx] = emb[c * D + d];
}

// ---- main: per-token argmin + gather + partial loss ------------------------
__global__ __launch_bounds__(BLK) void vq_main(
    const float* __restrict__ z_e, const float* __restrict__ emb,
    const float* __restrict__ embT, const float* __restrict__ esq,
    float* __restrict__ out_zq, float* __restrict__ out_idx,
    float* __restrict__ block_loss) {
  const int t = threadIdx.x;
  const int n = blockIdx.x * BLK + t;

  const float4* Z4 = reinterpret_cast<const float4*>(z_e + (size_t)n * D);

  float best = 3.402823466e38f;
  int   bidx = 0;

  for (int p = 0; p < NPANEL; ++p) {
    const float* Ebase = embT + p * PANEL;  // wave-uniform; row stride K
    float acc[PANEL];
#pragma unroll
    for (int c = 0; c < PANEL; ++c) acc[c] = 0.f;

    // 16 float4 chunks of this thread's z row; each feeds 4x32 FMAs.
    // d order ascending (i*4+dd) == R5's accumulation order (absmax 0).
#pragma unroll 2
    for (int i = 0; i < D / 4; ++i) {
      float4 v = Z4[i];                        // per-lane, L2/L3-hot re-read
      const float* e = Ebase + (size_t)(4 * i) * K;
#pragma unroll
      for (int c = 0; c < PANEL; ++c) acc[c] = fmaf(v.x, e[c], acc[c]);
      e += K;
#pragma unroll
      for (int c = 0; c < PANEL; ++c) acc[c] = fmaf(v.y, e[c], acc[c]);
      e += K;
#pragma unroll
      for (int c = 0; c < PANEL; ++c) acc[c] = fmaf(v.z, e[c], acc[c]);
      e += K;
#pragma unroll
      for (int c = 0; c < PANEL; ++c) acc[c] = fmaf(v.w, e[c], acc[c]);
    }

    const float* es = esq + p * PANEL;  // wave-uniform
#pragma unroll
    for (int c = 0; c < PANEL; ++c) {
      float s = fmaf(-2.f, acc[c], es[c]);
      // Ascending panel/c order + strict < == jnp.argmin first-min ties.
      if (s < best) { best = s; bidx = p * PANEL + c; }
    }
  }

  // Gather chosen code (divergent, codebook L2-hot); st = z + (q - z)
  // literally; z re-read from global (bitwise same values).
  float lsum = 0.f;
  {
    const float4* er = reinterpret_cast<const float4*>(emb + (size_t)bidx * D);
    float4* orow = reinterpret_cast<float4*>(out_zq + (size_t)n * D);
#pragma unroll 4
    for (int i = 0; i < D / 4; ++i) {
      float4 q = er[i];
      float4 zv = Z4[i];
      float dx = q.x - zv.x, dy = q.y - zv.y;
      float dz = q.z - zv.z, dw = q.w - zv.w;
      float4 st;
      st.x = zv.x + dx; st.y = zv.y + dy;
      st.z = zv.z + dz; st.w = zv.w + dw;
      orow[i] = st;
      lsum = fmaf(dx, dx, lsum);
      lsum = fmaf(dy, dy, lsum);
      lsum = fmaf(dz, dz, lsum);
      lsum = fmaf(dw, dw, lsum);
    }
  }

  out_idx[n] = (float)bidx;

  // Deterministic per-block loss reduction.
  __shared__ float red[BLK];
  red[t] = lsum;
  __syncthreads();
#pragma unroll
  for (int off = BLK / 2; off > 0; off >>= 1) {
    if (t < off) red[t] += red[t + off];
    __syncthreads();
  }
  if (t == 0) block_loss[blockIdx.x] = red[0];
}

// ---- finalize loss (deterministic tree) ------------------------------------
__global__ __launch_bounds__(256) void loss_finalize(
    const float* __restrict__ bl, float* __restrict__ out_loss) {
  __shared__ float sm[256];
  float s = 0.f;
  for (int i = threadIdx.x; i < NBLK; i += 256) s += bl[i];
  sm[threadIdx.x] = s;
  __syncthreads();
#pragma unroll
  for (int off = 128; off > 0; off >>= 1) {
    if (threadIdx.x < off) sm[threadIdx.x] += sm[threadIdx.x + off];
    __syncthreads();
  }
  if (threadIdx.x == 0) out_loss[0] = sm[0] * (1.0f / 16777216.0f);  // /(N*D)
}

extern "C" void kernel_launch(void* const* d_in, const int* in_sizes, int n_in,
                              void* d_out, int out_size, void* d_ws, size_t ws_size,
                              hipStream_t stream) {
  const float* z_e = (const float*)d_in[0];
  const float* emb = (const float*)d_in[1];

  float* out      = (float*)d_out;
  float* out_zq   = out;                          // N*D
  float* out_idx  = out + (size_t)N_TOK * D;      // N
  float* out_loss = out_idx + N_TOK;              // 1

  float* esq  = (float*)d_ws;            // K floats
  float* bl   = esq + K;                 // NBLK floats
  float* embT = bl + NBLK;               // K*D floats (128 KiB)

  esq_kernel<<<1, K, 0, stream>>>(emb, esq);
  embT_kernel<<<(K * D) / 512, 512, 0, stream>>>(emb, embT);
  vq_main<<<NBLK, BLK, 0, stream>>>(z_e, emb, embT, esq, out_zq, out_idx, bl);
  loss_finalize<<<1, 256, 0, stream>>>(bl, out_loss);
}